// Round 13
// baseline (1784.784 us; speedup 1.0000x reference)
//
#include <hip/hip_runtime.h>
#include <hip/hip_bf16.h>

#define E_CNT 500000
#define N_CNT 50000
#define DD 128
#define HH 256
#define LN_EPS 1e-5f
#define TPB_E 4                        // edge tiles (of 32) per block

typedef __attribute__((ext_vector_type(8))) short bh8;   // 8 x bf16 (MFMA A/B frag)
typedef __attribute__((ext_vector_type(4))) float fx4;   // MFMA C/D frag

__device__ __forceinline__ float b2f(short s) {
    return __uint_as_float(((unsigned)(unsigned short)s) << 16);
}
// paired f32->bf16 RNE via v_cvt_pk_bf16_f32 (1 instr / 2 values)
__device__ __forceinline__ unsigned f2b2(float lo, float hi) {
    float2 t; t.x = lo; t.y = hi;
    __hip_bfloat162 h2 = __float22bfloat162_rn(t);
    union { __hip_bfloat162 h; unsigned u; } cv; cv.h = h2; return cv.u;
}
__device__ __forceinline__ short f2b(float f) {   // scalar fallback (cold paths)
    unsigned x = __float_as_uint(f);
    x += 0x7fffu + ((x >> 16) & 1u);   // RNE
    return (short)(x >> 16);
}
__device__ __forceinline__ fx4 mfma16(bh8 a, bh8 b, fx4 c) {
    return __builtin_amdgcn_mfma_f32_16x16x32_bf16(a, b, c, 0, 0, 0);
}
__device__ __forceinline__ int swz128(int row, int k) {   // [*][128] bf16 tile
    return ((row * 128 + k) * 2) ^ ((row & 7) << 4);
}
__device__ __forceinline__ int swz256(int row, int c) {   // [*][256] bf16 tile
    return ((row * 256 + c) * 2) ^ ((row & 7) << 4);
}
__device__ __forceinline__ bh8 pack8(const float* s) {
    float4 f0 = *(const float4*)s, f1 = *(const float4*)(s + 4);
    union { unsigned u[4]; bh8 v; } cv;
    cv.u[0] = f2b2(f0.x, f0.y);
    cv.u[1] = f2b2(f0.z, f0.w);
    cv.u[2] = f2b2(f1.x, f1.y);
    cv.u[3] = f2b2(f1.z, f1.w);
    return cv.v;
}

// ---------------------------------------------------------------------------
// Weight transpose-convert: dst[n][k] = bf16(src[k][n]); src is [K][N] f32.
// ---------------------------------------------------------------------------
__global__ void wtrans(const float* __restrict__ src, short* __restrict__ dst,
                       int K, int N) {
    int idx = blockIdx.x * 256 + threadIdx.x;
    if (idx >= K * N) return;
    int n = idx / K, k = idx - n * K;
    dst[idx] = f2b(src[(size_t)k * N + n]);
}

// packed GEMM1 B for edge kernel: eW1a[n][k] = bf16(eW1[k][n]), k<128
__global__ void wtransA(const float* __restrict__ src, short* __restrict__ dst) {
    int idx = blockIdx.x * 256 + threadIdx.x;
    if (idx >= 256 * 128) return;
    int n = idx >> 7, k = idx & 127;
    dst[idx] = f2b(src[(size_t)k * 256 + n]);
}

// ---------------------------------------------------------------------------
// Table precompute: tabS[n][h] = bf16(nodes[n]@eW1[128:256]),
//                   tabR[n][h] = bf16(nodes[n]@eW1[256:384]).
// ---------------------------------------------------------------------------
__launch_bounds__(512, 2)
__global__ void table_kernel(const float* __restrict__ nodes,
                             const short* __restrict__ eW1t,   // [256][384]
                             short* __restrict__ tabS, short* __restrict__ tabR) {
    __shared__ char Abuf[128 * 128 * 2];
    const int tid = threadIdx.x;
    const int l = tid & 63, wid = tid >> 6;
    const int wm = wid >> 2, wn = wid & 3;
    const int n0 = blockIdx.x * 128;

    for (int it = 0; it < 4; ++it) {
        int c = tid + 512 * it;
        int row = c >> 4, cc = (c & 15) * 8;
        int n = n0 + row; if (n >= N_CNT) n = N_CNT - 1;
        *(bh8*)(Abuf + swz128(row, cc)) = pack8(nodes + (size_t)n * DD + cc);
    }
    __syncthreads();

    fx4 accS[4][4] = {}; fx4 accR[4][4] = {};
    #pragma unroll
    for (int kk = 0; kk < 4; ++kk) {
        int krow = kk * 32 + (l >> 4) * 8;
        bh8 a[4], bs[4], br[4];
        #pragma unroll
        for (int i = 0; i < 4; ++i)
            a[i] = *(const bh8*)(Abuf + swz128(wm * 64 + 16 * i + (l & 15), krow));
        #pragma unroll
        for (int j = 0; j < 4; ++j) {
            const short* bp = eW1t + (size_t)(wn * 64 + 16 * j + (l & 15)) * 384 + krow;
            bs[j] = *(const bh8*)(bp + 128);
            br[j] = *(const bh8*)(bp + 256);
        }
        #pragma unroll
        for (int i = 0; i < 4; ++i)
            #pragma unroll
            for (int j = 0; j < 4; ++j) {
                accS[i][j] = mfma16(a[i], bs[j], accS[i][j]);
                accR[i][j] = mfma16(a[i], br[j], accR[i][j]);
            }
    }
    #pragma unroll
    for (int i = 0; i < 4; ++i)
        #pragma unroll
        for (int r = 0; r < 4; ++r) {
            int row = wm * 64 + 16 * i + (l >> 4) * 4 + r;
            int n = n0 + row;
            if (n < N_CNT) {
                unsigned s01 = f2b2(accS[i][0][r], accS[i][1][r]);
                unsigned s23 = f2b2(accS[i][2][r], accS[i][3][r]);
                unsigned r01 = f2b2(accR[i][0][r], accR[i][1][r]);
                unsigned r23 = f2b2(accR[i][2][r], accR[i][3][r]);
                size_t base = (size_t)n * HH + (l & 15);
                tabS[base + wn * 64 +  0] = (short)s01;
                tabS[base + wn * 64 + 16] = (short)(s01 >> 16);
                tabS[base + wn * 64 + 32] = (short)s23;
                tabS[base + wn * 64 + 48] = (short)(s23 >> 16);
                tabR[base + wn * 64 +  0] = (short)r01;
                tabR[base + wn * 64 + 16] = (short)(r01 >> 16);
                tabR[base + wn * 64 + 32] = (short)r23;
                tabR[base + wn * 64 + 48] = (short)(r23 >> 16);
            }
        }
}

// ---------------------------------------------------------------------------
// Edge kernel v13: v12 structure made PERSISTENT over TPB_E tiles with
// cross-tile register prefetch (R4's idea, finally with a sane reg budget):
// while tile t computes GEMM1->LN->GEMM2 (~2-3us), tile t+1's edge rows,
// receivers, and table gathers are in flight into registers.
// launch_bounds(256,3): reg cap ~170 -> no spill at ~140 peak demand.
// ---------------------------------------------------------------------------
__launch_bounds__(256, 3)
__global__ void edge_kernel(const float* __restrict__ edges,
                            const int* __restrict__ senders,
                            const int* __restrict__ receivers,
                            const short* __restrict__ tabS,
                            const short* __restrict__ tabR,
                            const short* __restrict__ eW1a,   // [256][128]
                            const short* __restrict__ eW2t,   // [128][256]
                            const float* __restrict__ eb1,
                            const float* __restrict__ eg,
                            const float* __restrict__ ebt,
                            const float* __restrict__ eb2,
                            short* __restrict__ aggBF,        // [N][128] bf16
                            float* __restrict__ edges_out) {
    __shared__ short Abuf[32 * 128];     //  8KB edges tile (bf16, swizzled)
    __shared__ short Sbuf[32 * 256];     // 16KB table-sum, later H
    __shared__ float P[32][4][2];        //  1KB LN partials
    __shared__ int irecv[32];

    const int tid = threadIdx.x;
    const int l = tid & 63, wid = tid >> 6, lg = l >> 4, lo = l & 15;
    const int NTILE = (E_CNT + 31) / 32;          // 15625
    const int tile0 = blockIdx.x * TPB_E;
    const int ntile = min(TPB_E, NTILE - tile0);
    if (ntile <= 0) return;

    // tile-invariant per-column constants (hoisted out of the loop)
    const int wn = wid;                           // GEMM1: 4 waves = 4 col groups
    const int wm2 = wid >> 1, wn2 = wid & 1;      // GEMM2 decomposition
    float eb1c[4], egc[4], ebtc[4], eb2c[4];
    #pragma unroll
    for (int j = 0; j < 4; ++j) {
        int col = wn * 64 + 16 * j + lo;
        eb1c[j] = eb1[col]; egc[j] = eg[col]; ebtc[j] = ebt[col];
        eb2c[j] = eb2[wn2 * 64 + 16 * j + lo];
    }

    // next-tile register staging
    float4 ef[2][2];          // 32x128 f32 edge tile: 2 chunks x 8 floats
    bh8 ts[4], tr[4];         // table gathers: 4 chunks x 8 bf16 each
    int nrcv = 0;

    #define LOAD_TILE(T)                                                      \
    {                                                                         \
        int e0n = (T) * 32;                                                   \
        _Pragma("unroll")                                                     \
        for (int it = 0; it < 2; ++it) {                                      \
            int ch = tid + 256 * it;                                          \
            int row = ch >> 4, c = (ch & 15) * 8;                             \
            int e = e0n + row; if (e >= E_CNT) e = E_CNT - 1;                 \
            const float* p = edges + (size_t)e * DD + c;                      \
            ef[it][0] = *(const float4*)p;                                    \
            ef[it][1] = *(const float4*)(p + 4);                              \
        }                                                                     \
        if (tid < 32) {                                                       \
            int e = e0n + tid; if (e >= E_CNT) e = E_CNT - 1;                 \
            nrcv = receivers[e];                                              \
        }                                                                     \
        _Pragma("unroll")                                                     \
        for (int it = 0; it < 4; ++it) {                                      \
            int ch = tid + 256 * it;                                          \
            int row = ch >> 5, cc = (ch & 31) * 8;                            \
            int e = e0n + row; if (e >= E_CNT) e = E_CNT - 1;                 \
            ts[it] = *(const bh8*)(tabS + (size_t)senders[e] * HH + cc);      \
            tr[it] = *(const bh8*)(tabR + (size_t)receivers[e] * HH + cc);    \
        }                                                                     \
    }

    LOAD_TILE(tile0);   // prologue

    for (int t = 0; t < ntile; ++t) {
        const int e0 = (tile0 + t) * 32;

        // ---- P0: drain prefetched registers -> LDS ----
        #pragma unroll
        for (int it = 0; it < 2; ++it) {
            int ch = tid + 256 * it;
            int row = ch >> 4, c = (ch & 15) * 8;
            union { unsigned u[4]; bh8 v; } cv;
            cv.u[0] = f2b2(ef[it][0].x, ef[it][0].y);
            cv.u[1] = f2b2(ef[it][0].z, ef[it][0].w);
            cv.u[2] = f2b2(ef[it][1].x, ef[it][1].y);
            cv.u[3] = f2b2(ef[it][1].z, ef[it][1].w);
            *(bh8*)((char*)Abuf + swz128(row, c)) = cv.v;
        }
        #pragma unroll
        for (int it = 0; it < 4; ++it) {
            int ch = tid + 256 * it;
            int row = ch >> 5, cc = (ch & 31) * 8;
            union { unsigned u[4]; bh8 v; } cv;
            #pragma unroll
            for (int q = 0; q < 4; ++q) {
                float s0 = b2f(ts[it][2 * q])     + b2f(tr[it][2 * q]);
                float s1 = b2f(ts[it][2 * q + 1]) + b2f(tr[it][2 * q + 1]);
                cv.u[q] = f2b2(s0, s1);
            }
            *(bh8*)((char*)Sbuf + swz256(row, cc)) = cv.v;
        }
        if (tid < 32) irecv[tid] = nrcv;
        __syncthreads();

        // ---- issue next tile's loads; they fly through all compute below ----
        if (t + 1 < ntile) LOAD_TILE(tile0 + t + 1);

        // ---- GEMM1: A[32x128] @ W1a -> acc[32x256] ----
        fx4 acc[2][4] = {};
        #pragma unroll
        for (int kk = 0; kk < 4; ++kk) {
            int krow = kk * 32 + lg * 8;
            bh8 a[2], b[4];
            #pragma unroll
            for (int i = 0; i < 2; ++i)
                a[i] = *(const bh8*)((char*)Abuf + swz128(16 * i + lo, krow));
            #pragma unroll
            for (int j = 0; j < 4; ++j)
                b[j] = *(const bh8*)(eW1a + (size_t)(wn * 64 + 16 * j + lo) * 128 + krow);
            #pragma unroll
            for (int i = 0; i < 2; ++i)
                #pragma unroll
                for (int j = 0; j < 4; ++j)
                    acc[i][j] = mfma16(a[i], b[j], acc[i][j]);
        }

        // ---- epilogue 1: + table-sum + eb1, LN partials ----
        #pragma unroll
        for (int i = 0; i < 2; ++i)
            #pragma unroll
            for (int r = 0; r < 4; ++r) {
                int row = 16 * i + lg * 4 + r;
                float s = 0.f, q = 0.f;
                #pragma unroll
                for (int j = 0; j < 4; ++j) {
                    int col = wn * 64 + 16 * j + lo;
                    float v = acc[i][j][r] + eb1c[j] +
                              b2f(*(const short*)((char*)Sbuf + swz256(row, col)));
                    acc[i][j][r] = v;
                    s += v; q += v * v;
                }
                #pragma unroll
                for (int m = 1; m < 16; m <<= 1) {
                    s += __shfl_xor(s, m);
                    q += __shfl_xor(q, m);
                }
                if (lo == 0) { P[row][wn][0] = s; P[row][wn][1] = q; }
            }
        __syncthreads();   // Sbuf(table-sum) reads done; partials visible

        // ---- epilogue 2: LN + relu -> H into Sbuf ----
        #pragma unroll
        for (int i = 0; i < 2; ++i)
            #pragma unroll
            for (int r = 0; r < 4; ++r) {
                int row = 16 * i + lg * 4 + r;
                float s = P[row][0][0] + P[row][1][0] + P[row][2][0] + P[row][3][0];
                float q = P[row][0][1] + P[row][1][1] + P[row][2][1] + P[row][3][1];
                float mean = s * (1.0f / 256.0f);
                float var = q * (1.0f / 256.0f) - mean * mean;
                float rstd = rsqrtf(var + LN_EPS);
                float hv[4];
                #pragma unroll
                for (int j = 0; j < 4; ++j) {
                    float v = (acc[i][j][r] - mean) * rstd * egc[j] + ebtc[j];
                    hv[j] = fmaxf(v, 0.0f);
                }
                unsigned p01 = f2b2(hv[0], hv[1]);
                unsigned p23 = f2b2(hv[2], hv[3]);
                *(short*)((char*)Sbuf + swz256(row, wn * 64 +  0 + lo)) = (short)p01;
                *(short*)((char*)Sbuf + swz256(row, wn * 64 + 16 + lo)) = (short)(p01 >> 16);
                *(short*)((char*)Sbuf + swz256(row, wn * 64 + 32 + lo)) = (short)p23;
                *(short*)((char*)Sbuf + swz256(row, wn * 64 + 48 + lo)) = (short)(p23 >> 16);
            }
        __syncthreads();

        // ---- GEMM2: H[32x256] @ eW2 -> [32x128] ----
        fx4 acc2[4] = {};
        #pragma unroll
        for (int kk = 0; kk < 8; ++kk) {
            int krow = kk * 32 + lg * 8;
            bh8 a = *(const bh8*)((char*)Sbuf + swz256(wm2 * 16 + lo, krow));
            #pragma unroll
            for (int j = 0; j < 4; ++j) {
                bh8 b = *(const bh8*)(eW2t + (size_t)(wn2 * 64 + 16 * j + lo) * HH + krow);
                acc2[j] = mfma16(a, b, acc2[j]);
            }
        }
        #pragma unroll
        for (int r = 0; r < 4; ++r) {
            int row = wm2 * 16 + lg * 4 + r;
            int e = e0 + row;
            int rcv = irecv[row];
            #pragma unroll
            for (int j = 0; j < 4; ++j) {
                int col = wn2 * 64 + 16 * j + lo;
                float upd = acc2[j][r] + eb2c[j];
                float par = __shfl_xor(upd, 1);
                if (e < E_CNT) {
                    float res = b2f(*(const short*)((char*)Abuf + swz128(row, col)));
                    edges_out[(size_t)e * DD + col] = upd + res;
                    if ((lo & 1) == 0) {
                        unsigned pk = f2b2(upd, par);
                        short* p = aggBF + (size_t)rcv * DD + col;
                        asm volatile("global_atomic_pk_add_bf16 %0, %1, off"
                                     :: "v"(p), "v"(pk) : "memory");
                    }
                }
            }
        }
        __syncthreads();   // Abuf/Sbuf fully consumed; next P0 may overwrite
    }
    #undef LOAD_TILE
}

// ---------------------------------------------------------------------------
// Node kernel: nx=[nodes|aggBF] -> GEMM1 (K=256) -> LN/relu -> GEMM2 + nb2 + nodes
// ---------------------------------------------------------------------------
__launch_bounds__(512, 2)
__global__ void node_kernel(const float* __restrict__ nodes,
                            const short* __restrict__ aggBF,  // [N][128] bf16
                            const short* __restrict__ nW1t,   // [256][256]
                            const short* __restrict__ nW2t,   // [128][256]
                            const float* __restrict__ nb1,
                            const float* __restrict__ ng,
                            const float* __restrict__ nbt,
                            const float* __restrict__ nb2,
                            float* __restrict__ nodes_out) {
    __shared__ char X[64 * 256 * 2];
    __shared__ float P[64][4][2];

    const int tid = threadIdx.x;
    const int l = tid & 63, wid = tid >> 6;
    const int n0 = blockIdx.x * 64;

    #pragma unroll
    for (int it = 0; it < 4; ++it) {
        int c = tid + 512 * it;
        int row = c >> 5, cc = (c & 31) * 8;
        int n = n0 + row; if (n >= N_CNT) n = N_CNT - 1;
        bh8 v;
        if (cc < DD) v = pack8(nodes + (size_t)n * DD + cc);
        else         v = *(const bh8*)(aggBF + (size_t)n * DD + (cc - DD));
        *(bh8*)(X + swz256(row, cc)) = v;
    }
    __syncthreads();

    const int wm = wid >> 2, wn = wid & 3;
    fx4 acc[2][4] = {};
    #pragma unroll
    for (int kk = 0; kk < 8; ++kk) {
        int krow = kk * 32 + (l >> 4) * 8;
        bh8 a[2], b[4];
        #pragma unroll
        for (int i = 0; i < 2; ++i)
            a[i] = *(const bh8*)(X + swz256(wm * 32 + 16 * i + (l & 15), krow));
        #pragma unroll
        for (int j = 0; j < 4; ++j)
            b[j] = *(const bh8*)(nW1t + (size_t)(wn * 64 + 16 * j + (l & 15)) * 256 + krow);
        #pragma unroll
        for (int i = 0; i < 2; ++i)
            #pragma unroll
            for (int j = 0; j < 4; ++j)
                acc[i][j] = mfma16(a[i], b[j], acc[i][j]);
    }
    __syncthreads();

    float nb1c[4], ngc[4], nbtc[4];
    #pragma unroll
    for (int j = 0; j < 4; ++j) {
        int col = wn * 64 + 16 * j + (l & 15);
        nb1c[j] = nb1[col]; ngc[j] = ng[col]; nbtc[j] = nbt[col];
    }
    #pragma unroll
    for (int i = 0; i < 2; ++i)
        #pragma unroll
        for (int r = 0; r < 4; ++r) {
            int row = wm * 32 + 16 * i + (l >> 4) * 4 + r;
            float s = 0.f, q = 0.f;
            #pragma unroll
            for (int j = 0; j < 4; ++j) {
                float v = acc[i][j][r] + nb1c[j];
                acc[i][j][r] = v;
                s += v; q += v * v;
            }
            #pragma unroll
            for (int m = 1; m < 16; m <<= 1) {
                s += __shfl_xor(s, m);
                q += __shfl_xor(q, m);
            }
            if ((l & 15) == 0) { P[row][wn][0] = s; P[row][wn][1] = q; }
        }
    __syncthreads();

    #pragma unroll
    for (int i = 0; i < 2; ++i)
        #pragma unroll
        for (int r = 0; r < 4; ++r) {
            int row = wm * 32 + 16 * i + (l >> 4) * 4 + r;
            float s = P[row][0][0] + P[row][1][0] + P[row][2][0] + P[row][3][0];
            float q = P[row][0][1] + P[row][1][1] + P[row][2][1] + P[row][3][1];
            float mean = s * (1.0f / 256.0f);
            float var = q * (1.0f / 256.0f) - mean * mean;
            float rstd = rsqrtf(var + LN_EPS);
            float hv[4];
            #pragma unroll
            for (int j = 0; j < 4; ++j) {
                float v = (acc[i][j][r] - mean) * rstd * ngc[j] + nbtc[j];
                hv[j] = fmaxf(v, 0.0f);
            }
            unsigned p01 = f2b2(hv[0], hv[1]);
            unsigned p23 = f2b2(hv[2], hv[3]);
            int c0 = wn * 64 + (l & 15);
            *(short*)(X + swz256(row, c0 +  0)) = (short)p01;
            *(short*)(X + swz256(row, c0 + 16)) = (short)(p01 >> 16);
            *(short*)(X + swz256(row, c0 + 32)) = (short)p23;
            *(short*)(X + swz256(row, c0 + 48)) = (short)(p23 >> 16);
        }
    __syncthreads();

    const int wm2 = wid >> 1, wn2 = wid & 1;
    fx4 acc2[4] = {};
    #pragma unroll
    for (int kk = 0; kk < 8; ++kk) {
        int krow = kk * 32 + (l >> 4) * 8;
        bh8 a = *(const bh8*)(X + swz256(wm2 * 16 + (l & 15), krow));
        #pragma unroll
        for (int j = 0; j < 4; ++j) {
            bh8 b = *(const bh8*)(nW2t + (size_t)(wn2 * 64 + 16 * j + (l & 15)) * 256 + krow);
            acc2[j] = mfma16(a, b, acc2[j]);
        }
    }
    float nb2c[4];
    #pragma unroll
    for (int j = 0; j < 4; ++j) nb2c[j] = nb2[wn2 * 64 + 16 * j + (l & 15)];
    #pragma unroll
    for (int r = 0; r < 4; ++r) {
        int row = wm2 * 16 + (l >> 4) * 4 + r;
        int n = n0 + row;
        if (n < N_CNT) {
            #pragma unroll
            for (int j = 0; j < 4; ++j) {
                int col = wn2 * 64 + 16 * j + (l & 15);
                nodes_out[(size_t)n * DD + col] =
                    acc2[j][r] + nb2c[j] + nodes[(size_t)n * DD + col];
            }
        }
    }
}

// ---------------------------------------------------------------------------
extern "C" void kernel_launch(void* const* d_in, const int* in_sizes, int n_in,
                              void* d_out, int out_size, void* d_ws, size_t ws_size,
                              hipStream_t stream) {
    const float* nodes = (const float*)d_in[0];
    const float* edges = (const float*)d_in[1];
    const int* senders = (const int*)d_in[2];
    const int* receivers = (const int*)d_in[3];
    const float* eW1 = (const float*)d_in[4];
    const float* eb1 = (const float*)d_in[5];
    const float* eg  = (const float*)d_in[6];
    const float* ebt = (const float*)d_in[7];
    const float* eW2 = (const float*)d_in[8];
    const float* eb2 = (const float*)d_in[9];
    const float* nW1 = (const float*)d_in[10];
    const float* nb1 = (const float*)d_in[11];
    const float* ng  = (const float*)d_in[12];
    const float* nbt = (const float*)d_in[13];
    const float* nW2 = (const float*)d_in[14];
    const float* nb2 = (const float*)d_in[15];

    char* ws = (char*)d_ws;
    short* aggBF = (short*)(ws + 0);            // 12,800,000 B [N][128] bf16
    short* eW1t  = (short*)(ws + 12800000);     //    196,608 B [256][384]
    short* eW2t  = (short*)(ws + 12996608);     //     65,536 B [128][256]
    short* nW1t  = (short*)(ws + 13062144);     //    131,072 B [256][256]
    short* nW2t  = (short*)(ws + 13193216);     //     65,536 B [128][256]
    short* eW1a  = (short*)(ws + 13258752);     //     65,536 B [256][128]
    short* tabS  = (short*)(ws + 13324288);     // 25,600,000 B [N][256]
    short* tabR  = (short*)(ws + 38924288);     // 25,600,000 B [N][256]

    float* nodes_out = (float*)d_out;
    float* edges_out = nodes_out + (size_t)N_CNT * DD;

    hipMemsetAsync(aggBF, 0, (size_t)N_CNT * DD * sizeof(short), stream);

    wtrans<<<(384 * 256 + 255) / 256, 256, 0, stream>>>(eW1, eW1t, 384, 256);
    wtrans<<<(256 * 128 + 255) / 256, 256, 0, stream>>>(eW2, eW2t, 256, 128);
    wtrans<<<(256 * 256 + 255) / 256, 256, 0, stream>>>(nW1, nW1t, 256, 256);
    wtrans<<<(256 * 128 + 255) / 256, 256, 0, stream>>>(nW2, nW2t, 256, 128);
    wtransA<<<(256 * 128 + 255) / 256, 256, 0, stream>>>(eW1, eW1a);

    table_kernel<<<(N_CNT + 127) / 128, 512, 0, stream>>>(nodes, eW1t, tabS, tabR);

    const int NTILE = (E_CNT + 31) / 32;               // 15625
    edge_kernel<<<(NTILE + TPB_E - 1) / TPB_E, 256, 0, stream>>>(
        edges, senders, receivers, tabS, tabR, eW1a, eW2t,
        eb1, eg, ebt, eb2, aggBF, edges_out);

    node_kernel<<<(N_CNT + 63) / 64, 512, 0, stream>>>(
        nodes, aggBF, nW1t, nW2t, nb1, ng, nbt, nb2, nodes_out);
}

// Round 14
// 915.784 us; speedup vs baseline: 1.9489x; 1.9489x over previous
//
#include <hip/hip_runtime.h>
#include <hip/hip_bf16.h>

#define E_CNT 500000
#define N_CNT 50000
#define DD 128
#define HH 256
#define LN_EPS 1e-5f
#define TPB_E 8                        // edge tiles (of 32) per block
#define PLANE_B 16896                  // plane bytes: 16 pairs x 1040 used; H pad

typedef __attribute__((ext_vector_type(8))) short bh8;   // 8 x bf16 (MFMA A/B frag)
typedef __attribute__((ext_vector_type(4))) float fx4;   // MFMA C/D frag

__device__ __forceinline__ float b2f(short s) {
    return __uint_as_float(((unsigned)(unsigned short)s) << 16);
}
__device__ __forceinline__ unsigned f2b2(float lo, float hi) {
    float2 t; t.x = lo; t.y = hi;
    __hip_bfloat162 h2 = __float22bfloat162_rn(t);
    union { __hip_bfloat162 h; unsigned u; } cv; cv.h = h2; return cv.u;
}
__device__ __forceinline__ short f2b(float f) {
    unsigned x = __float_as_uint(f);
    x += 0x7fffu + ((x >> 16) & 1u);   // RNE
    return (short)(x >> 16);
}
__device__ __forceinline__ fx4 mfma16(bh8 a, bh8 b, fx4 c) {
    return __builtin_amdgcn_mfma_f32_16x16x32_bf16(a, b, c, 0, 0, 0);
}
__device__ __forceinline__ int swz128(int row, int k) {   // [*][128] bf16 tile
    return ((row * 128 + k) * 2) ^ ((row & 7) << 4);
}
__device__ __forceinline__ int swz256(int row, int c) {   // [*][256] bf16 tile
    return ((row * 256 + c) * 2) ^ ((row & 7) << 4);
}
__device__ __forceinline__ bh8 pack8(const float* s) {
    float4 f0 = *(const float4*)s, f1 = *(const float4*)(s + 4);
    union { unsigned u[4]; bh8 v; } cv;
    cv.u[0] = f2b2(f0.x, f0.y);
    cv.u[1] = f2b2(f0.z, f0.w);
    cv.u[2] = f2b2(f1.x, f1.y);
    cv.u[3] = f2b2(f1.z, f1.w);
    return cv.v;
}
// async global->LDS, 16B/lane; dest = wave-uniform base + lane*16 (HW rule)
__device__ __forceinline__ void dma16(const void* g, void* l) {
    __builtin_amdgcn_global_load_lds(
        (const __attribute__((address_space(1))) void*)g,
        (__attribute__((address_space(3))) void*)l, 16, 0, 0);
}

// ---------------------------------------------------------------------------
__global__ void wtrans(const float* __restrict__ src, short* __restrict__ dst,
                       int K, int N) {
    int idx = blockIdx.x * 256 + threadIdx.x;
    if (idx >= K * N) return;
    int n = idx / K, k = idx - n * K;
    dst[idx] = f2b(src[(size_t)k * N + n]);
}

__global__ void wtransA(const float* __restrict__ src, short* __restrict__ dst) {
    int idx = blockIdx.x * 256 + threadIdx.x;
    if (idx >= 256 * 128) return;
    int n = idx >> 7, k = idx & 127;
    dst[idx] = f2b(src[(size_t)k * 256 + n]);
}

// ---------------------------------------------------------------------------
// Table precompute: tabS[n][h] = bf16(nodes[n]@eW1[128:256]),
//                   tabR[n][h] = bf16(nodes[n]@eW1[256:384]).
// ---------------------------------------------------------------------------
__launch_bounds__(512, 2)
__global__ void table_kernel(const float* __restrict__ nodes,
                             const short* __restrict__ eW1t,   // [256][384]
                             short* __restrict__ tabS, short* __restrict__ tabR) {
    __shared__ char Abuf[128 * 128 * 2];
    const int tid = threadIdx.x;
    const int l = tid & 63, wid = tid >> 6;
    const int wm = wid >> 2, wn = wid & 3;
    const int n0 = blockIdx.x * 128;

    for (int it = 0; it < 4; ++it) {
        int c = tid + 512 * it;
        int row = c >> 4, cc = (c & 15) * 8;
        int n = n0 + row; if (n >= N_CNT) n = N_CNT - 1;
        *(bh8*)(Abuf + swz128(row, cc)) = pack8(nodes + (size_t)n * DD + cc);
    }
    __syncthreads();

    fx4 accS[4][4] = {}; fx4 accR[4][4] = {};
    #pragma unroll
    for (int kk = 0; kk < 4; ++kk) {
        int krow = kk * 32 + (l >> 4) * 8;
        bh8 a[4], bs[4], br[4];
        #pragma unroll
        for (int i = 0; i < 4; ++i)
            a[i] = *(const bh8*)(Abuf + swz128(wm * 64 + 16 * i + (l & 15), krow));
        #pragma unroll
        for (int j = 0; j < 4; ++j) {
            const short* bp = eW1t + (size_t)(wn * 64 + 16 * j + (l & 15)) * 384 + krow;
            bs[j] = *(const bh8*)(bp + 128);
            br[j] = *(const bh8*)(bp + 256);
        }
        #pragma unroll
        for (int i = 0; i < 4; ++i)
            #pragma unroll
            for (int j = 0; j < 4; ++j) {
                accS[i][j] = mfma16(a[i], bs[j], accS[i][j]);
                accR[i][j] = mfma16(a[i], br[j], accR[i][j]);
            }
    }
    #pragma unroll
    for (int i = 0; i < 4; ++i)
        #pragma unroll
        for (int r = 0; r < 4; ++r) {
            int row = wm * 64 + 16 * i + (l >> 4) * 4 + r;
            int n = n0 + row;
            if (n < N_CNT) {
                unsigned s01 = f2b2(accS[i][0][r], accS[i][1][r]);
                unsigned s23 = f2b2(accS[i][2][r], accS[i][3][r]);
                unsigned r01 = f2b2(accR[i][0][r], accR[i][1][r]);
                unsigned r23 = f2b2(accR[i][2][r], accR[i][3][r]);
                size_t base = (size_t)n * HH + (l & 15);
                tabS[base + wn * 64 +  0] = (short)s01;
                tabS[base + wn * 64 + 16] = (short)(s01 >> 16);
                tabS[base + wn * 64 + 32] = (short)s23;
                tabS[base + wn * 64 + 48] = (short)(s23 >> 16);
                tabR[base + wn * 64 +  0] = (short)r01;
                tabR[base + wn * 64 + 16] = (short)(r01 >> 16);
                tabR[base + wn * 64 + 32] = (short)r23;
                tabR[base + wn * 64 + 48] = (short)(r23 >> 16);
            }
        }
}

// ---------------------------------------------------------------------------
// Edge kernel v14: persistent over TPB_E tiles; table gathers prefetched one
// tile ahead via global_load_lds into DOUBLE-BUFFERED LDS planes (zero VGPR
// cost -> no spill, unlike R4/R5/R13). Counted-wait: single vmcnt(0) per tile,
// ~2-3us after issue. Edge rows prefetched in 16 regs (small, spill-safe).
// Planes: tabS/tabR rows in pairs at 1040B stride (ep1 reads conflict-free);
// H reuses current tabS plane as flat [32][264] (528B stride, b128-aligned).
// ---------------------------------------------------------------------------
__launch_bounds__(256, 2)
__global__ void edge_kernel(const float* __restrict__ edges,
                            const int* __restrict__ senders,
                            const int* __restrict__ receivers,
                            const short* __restrict__ tabS,
                            const short* __restrict__ tabR,
                            const short* __restrict__ eW1a,   // [256][128]
                            const short* __restrict__ eW2t,   // [128][256]
                            const float* __restrict__ eb1,
                            const float* __restrict__ eg,
                            const float* __restrict__ ebt,
                            const float* __restrict__ eb2,
                            short* __restrict__ aggBF,        // [N][128] bf16
                            float* __restrict__ edges_out) {
    __shared__ short Abuf[32 * 128];          //  8KB edges tile (bf16, swizzled)
    __shared__ char planes[4][PLANE_B];       // 66KB: [buf][S=0/R=1]
    __shared__ float P[32][4][2];             //  1KB LN partials
    __shared__ int irecv[32];

    const int tid = threadIdx.x;
    const int l = tid & 63, wid = tid >> 6, lg = l >> 4, lo = l & 15;
    const int NTILE = (E_CNT + 31) / 32;      // 15625
    const int tile0 = blockIdx.x * TPB_E;
    const int ntile = min(TPB_E, NTILE - tile0);
    if (ntile <= 0) return;

    const int wn = wid;                       // GEMM1: 4 waves = 4 col groups
    const int wm2 = wid >> 1, wn2 = wid & 1;  // GEMM2 decomposition
    float eb1c[4], egc[4], ebtc[4], eb2c[4];
    #pragma unroll
    for (int j = 0; j < 4; ++j) {
        int col = wn * 64 + 16 * j + lo;
        eb1c[j] = eb1[col]; egc[j] = eg[col]; ebtc[j] = ebt[col];
        eb2c[j] = eb2[wn2 * 64 + 16 * j + lo];
    }

    float4 ef[2][2];      // next-tile edge rows (16 VGPR)
    int nrcv = 0;

    // issue 8 DMAs/wave for tile T's tables into buffer b
    #define DMA_TILE(T, b)                                                    \
    {                                                                         \
        int e0n = (T) * 32;                                                   \
        _Pragma("unroll")                                                     \
        for (int q = 0; q < 8; ++q) {                                         \
            int qq = wid * 8 + q;                                             \
            int pr = qq & 15;                                                 \
            int r  = 2 * pr + (l >> 5);                                       \
            int e  = e0n + r; if (e >= E_CNT) e = E_CNT - 1;                  \
            int idx = (qq < 16 ? senders : receivers)[e];                     \
            const short* src = (qq < 16 ? tabS : tabR)                        \
                               + (size_t)idx * HH + (l & 31) * 8;             \
            char* dst = planes[(b) * 2 + (qq < 16 ? 0 : 1)] + pr * 1040;      \
            dma16(src, dst);                                                  \
        }                                                                     \
    }

    #define LOAD_EDGE(T)                                                      \
    {                                                                         \
        int e0n = (T) * 32;                                                   \
        _Pragma("unroll")                                                     \
        for (int it = 0; it < 2; ++it) {                                      \
            int ch = tid + 256 * it;                                          \
            int row = ch >> 4, c = (ch & 15) * 8;                             \
            int e = e0n + row; if (e >= E_CNT) e = E_CNT - 1;                 \
            const float* p = edges + (size_t)e * DD + c;                      \
            ef[it][0] = *(const float4*)p;                                    \
            ef[it][1] = *(const float4*)(p + 4);                              \
        }                                                                     \
        if (tid < 32) {                                                       \
            int e = e0n + tid; if (e >= E_CNT) e = E_CNT - 1;                 \
            nrcv = receivers[e];                                              \
        }                                                                     \
    }

    // prologue: tile0's edges + tables
    LOAD_EDGE(tile0);
    DMA_TILE(tile0, 0);
    asm volatile("s_waitcnt vmcnt(0)" ::: "memory");
    __syncthreads();

    for (int t = 0; t < ntile; ++t) {
        const int e0 = (tile0 + t) * 32;
        const int cb = t & 1;
        const char* TSp = planes[cb * 2 + 0];
        const char* TRp = planes[cb * 2 + 1];
        short* Hp = (short*)planes[cb * 2 + 0];   // H overlays tabS after ep1

        // ---- P0: drain edge registers -> Abuf; publish receivers ----
        #pragma unroll
        for (int it = 0; it < 2; ++it) {
            int ch = tid + 256 * it;
            int row = ch >> 4, c = (ch & 15) * 8;
            union { unsigned u[4]; bh8 v; } cv;
            cv.u[0] = f2b2(ef[it][0].x, ef[it][0].y);
            cv.u[1] = f2b2(ef[it][0].z, ef[it][0].w);
            cv.u[2] = f2b2(ef[it][1].x, ef[it][1].y);
            cv.u[3] = f2b2(ef[it][1].z, ef[it][1].w);
            *(bh8*)((char*)Abuf + swz128(row, c)) = cv.v;
        }
        if (tid < 32) irecv[tid] = nrcv;
        __syncthreads();

        // ---- issue tile t+1: edge regs + table DMAs (fly through compute) ----
        if (t + 1 < ntile) {
            LOAD_EDGE(tile0 + t + 1);
            DMA_TILE(tile0 + t + 1, (t + 1) & 1);
        }

        // ---- GEMM1: A[32x128] @ W1a -> acc[32x256] ----
        fx4 acc[2][4] = {};
        #pragma unroll
        for (int kk = 0; kk < 4; ++kk) {
            int krow = kk * 32 + lg * 8;
            bh8 a[2], b[4];
            #pragma unroll
            for (int i = 0; i < 2; ++i)
                a[i] = *(const bh8*)((char*)Abuf + swz128(16 * i + lo, krow));
            #pragma unroll
            for (int j = 0; j < 4; ++j)
                b[j] = *(const bh8*)(eW1a + (size_t)(wn * 64 + 16 * j + lo) * 128 + krow);
            #pragma unroll
            for (int i = 0; i < 2; ++i)
                #pragma unroll
                for (int j = 0; j < 4; ++j)
                    acc[i][j] = mfma16(a[i], b[j], acc[i][j]);
        }

        // ---- ep1: + tabS + tabR + eb1, LN partials ----
        // table cell (row,col) at plane + (row>>1)*1040 + (row&1)*512 + col*2
        #pragma unroll
        for (int i = 0; i < 2; ++i)
            #pragma unroll
            for (int r = 0; r < 4; ++r) {
                int row = 16 * i + lg * 4 + r;
                int rb = (row >> 1) * 1040 + (row & 1) * 512;
                float s = 0.f, q = 0.f;
                #pragma unroll
                for (int j = 0; j < 4; ++j) {
                    int col = wn * 64 + 16 * j + lo;
                    float tv = b2f(*(const short*)(TSp + rb + col * 2)) +
                               b2f(*(const short*)(TRp + rb + col * 2));
                    float v = acc[i][j][r] + eb1c[j] + tv;
                    acc[i][j][r] = v;
                    s += v; q += v * v;
                }
                #pragma unroll
                for (int m = 1; m < 16; m <<= 1) {
                    s += __shfl_xor(s, m);
                    q += __shfl_xor(q, m);
                }
                if (lo == 0) { P[row][wn][0] = s; P[row][wn][1] = q; }
            }
        __syncthreads();   // all table reads done; partials visible

        // ---- ep2: LN + relu -> H into Hp [32][264] ----
        #pragma unroll
        for (int i = 0; i < 2; ++i)
            #pragma unroll
            for (int r = 0; r < 4; ++r) {
                int row = 16 * i + lg * 4 + r;
                float s = P[row][0][0] + P[row][1][0] + P[row][2][0] + P[row][3][0];
                float q = P[row][0][1] + P[row][1][1] + P[row][2][1] + P[row][3][1];
                float mean = s * (1.0f / 256.0f);
                float var = q * (1.0f / 256.0f) - mean * mean;
                float rstd = rsqrtf(var + LN_EPS);
                float hv[4];
                #pragma unroll
                for (int j = 0; j < 4; ++j) {
                    float v = (acc[i][j][r] - mean) * rstd * egc[j] + ebtc[j];
                    hv[j] = fmaxf(v, 0.0f);
                }
                unsigned p01 = f2b2(hv[0], hv[1]);
                unsigned p23 = f2b2(hv[2], hv[3]);
                int c0 = wn * 64 + lo;
                Hp[row * 264 + c0 +  0] = (short)p01;
                Hp[row * 264 + c0 + 16] = (short)(p01 >> 16);
                Hp[row * 264 + c0 + 32] = (short)p23;
                Hp[row * 264 + c0 + 48] = (short)(p23 >> 16);
            }
        __syncthreads();

        // ---- GEMM2: H[32x256] @ eW2 -> [32x128] ----
        fx4 acc2[4] = {};
        #pragma unroll
        for (int kk = 0; kk < 8; ++kk) {
            int krow = kk * 32 + lg * 8;
            bh8 a = *(const bh8*)(Hp + (wm2 * 16 + lo) * 264 + krow);
            #pragma unroll
            for (int j = 0; j < 4; ++j) {
                bh8 b = *(const bh8*)(eW2t + (size_t)(wn2 * 64 + 16 * j + lo) * HH + krow);
                acc2[j] = mfma16(a, b, acc2[j]);
            }
        }
        #pragma unroll
        for (int r = 0; r < 4; ++r) {
            int row = wm2 * 16 + lg * 4 + r;
            int e = e0 + row;
            int rcv = irecv[row];
            #pragma unroll
            for (int j = 0; j < 4; ++j) {
                int col = wn2 * 64 + 16 * j + lo;
                float upd = acc2[j][r] + eb2c[j];
                float par = __shfl_xor(upd, 1);
                if (e < E_CNT) {
                    float res = b2f(*(const short*)((char*)Abuf + swz128(row, col)));
                    edges_out[(size_t)e * DD + col] = upd + res;
                    if ((lo & 1) == 0) {
                        unsigned pk = f2b2(upd, par);
                        short* p = aggBF + (size_t)rcv * DD + col;
                        asm volatile("global_atomic_pk_add_bf16 %0, %1, off"
                                     :: "v"(p), "v"(pk) : "memory");
                    }
                }
            }
        }
        // drain tile t+1's DMAs (issued ~full tile ago -> nearly free) + close
        asm volatile("s_waitcnt vmcnt(0)" ::: "memory");
        __syncthreads();
    }
    #undef DMA_TILE
    #undef LOAD_EDGE
}

// ---------------------------------------------------------------------------
// Node kernel: nx=[nodes|aggBF] -> GEMM1 (K=256) -> LN/relu -> GEMM2 + nb2 + nodes
// ---------------------------------------------------------------------------
__launch_bounds__(512, 2)
__global__ void node_kernel(const float* __restrict__ nodes,
                            const short* __restrict__ aggBF,  // [N][128] bf16
                            const short* __restrict__ nW1t,   // [256][256]
                            const short* __restrict__ nW2t,   // [128][256]
                            const float* __restrict__ nb1,
                            const float* __restrict__ ng,
                            const float* __restrict__ nbt,
                            const float* __restrict__ nb2,
                            float* __restrict__ nodes_out) {
    __shared__ char X[64 * 256 * 2];
    __shared__ float P[64][4][2];

    const int tid = threadIdx.x;
    const int l = tid & 63, wid = tid >> 6;
    const int n0 = blockIdx.x * 64;

    #pragma unroll
    for (int it = 0; it < 4; ++it) {
        int c = tid + 512 * it;
        int row = c >> 5, cc = (c & 31) * 8;
        int n = n0 + row; if (n >= N_CNT) n = N_CNT - 1;
        bh8 v;
        if (cc < DD) v = pack8(nodes + (size_t)n * DD + cc);
        else         v = *(const bh8*)(aggBF + (size_t)n * DD + (cc - DD));
        *(bh8*)(X + swz256(row, cc)) = v;
    }
    __syncthreads();

    const int wm = wid >> 2, wn = wid & 3;
    fx4 acc[2][4] = {};
    #pragma unroll
    for (int kk = 0; kk < 8; ++kk) {
        int krow = kk * 32 + (l >> 4) * 8;
        bh8 a[2], b[4];
        #pragma unroll
        for (int i = 0; i < 2; ++i)
            a[i] = *(const bh8*)(X + swz256(wm * 32 + 16 * i + (l & 15), krow));
        #pragma unroll
        for (int j = 0; j < 4; ++j)
            b[j] = *(const bh8*)(nW1t + (size_t)(wn * 64 + 16 * j + (l & 15)) * 256 + krow);
        #pragma unroll
        for (int i = 0; i < 2; ++i)
            #pragma unroll
            for (int j = 0; j < 4; ++j)
                acc[i][j] = mfma16(a[i], b[j], acc[i][j]);
    }
    __syncthreads();

    float nb1c[4], ngc[4], nbtc[4];
    #pragma unroll
    for (int j = 0; j < 4; ++j) {
        int col = wn * 64 + 16 * j + (l & 15);
        nb1c[j] = nb1[col]; ngc[j] = ng[col]; nbtc[j] = nbt[col];
    }
    #pragma unroll
    for (int i = 0; i < 2; ++i)
        #pragma unroll
        for (int r = 0; r < 4; ++r) {
            int row = wm * 32 + 16 * i + (l >> 4) * 4 + r;
            float s = 0.f, q = 0.f;
            #pragma unroll
            for (int j = 0; j < 4; ++j) {
                float v = acc[i][j][r] + nb1c[j];
                acc[i][j][r] = v;
                s += v; q += v * v;
            }
            #pragma unroll
            for (int m = 1; m < 16; m <<= 1) {
                s += __shfl_xor(s, m);
                q += __shfl_xor(q, m);
            }
            if ((l & 15) == 0) { P[row][wn][0] = s; P[row][wn][1] = q; }
        }
    __syncthreads();

    #pragma unroll
    for (int i = 0; i < 2; ++i)
        #pragma unroll
        for (int r = 0; r < 4; ++r) {
            int row = wm * 32 + 16 * i + (l >> 4) * 4 + r;
            float s = P[row][0][0] + P[row][1][0] + P[row][2][0] + P[row][3][0];
            float q = P[row][0][1] + P[row][1][1] + P[row][2][1] + P[row][3][1];
            float mean = s * (1.0f / 256.0f);
            float var = q * (1.0f / 256.0f) - mean * mean;
            float rstd = rsqrtf(var + LN_EPS);
            float hv[4];
            #pragma unroll
            for (int j = 0; j < 4; ++j) {
                float v = (acc[i][j][r] - mean) * rstd * ngc[j] + nbtc[j];
                hv[j] = fmaxf(v, 0.0f);
            }
            unsigned p01 = f2b2(hv[0], hv[1]);
            unsigned p23 = f2b2(hv[2], hv[3]);
            int c0 = wn * 64 + (l & 15);
            *(short*)(X + swz256(row, c0 +  0)) = (short)p01;
            *(short*)(X + swz256(row, c0 + 16)) = (short)(p01 >> 16);
            *(short*)(X + swz256(row, c0 + 32)) = (short)p23;
            *(short*)(X + swz256(row, c0 + 48)) = (short)(p23 >> 16);
        }
    __syncthreads();

    const int wm2 = wid >> 1, wn2 = wid & 1;
    fx4 acc2[4] = {};
    #pragma unroll
    for (int kk = 0; kk < 8; ++kk) {
        int krow = kk * 32 + (l >> 4) * 8;
        bh8 a = *(const bh8*)(X + swz256(wm2 * 16 + (l & 15), krow));
        #pragma unroll
        for (int j = 0; j < 4; ++j) {
            bh8 b = *(const bh8*)(nW2t + (size_t)(wn2 * 64 + 16 * j + (l & 15)) * 256 + krow);
            acc2[j] = mfma16(a, b, acc2[j]);
        }
    }
    float nb2c[4];
    #pragma unroll
    for (int j = 0; j < 4; ++j) nb2c[j] = nb2[wn2 * 64 + 16 * j + (l & 15)];
    #pragma unroll
    for (int r = 0; r < 4; ++r) {
        int row = wm2 * 16 + (l >> 4) * 4 + r;
        int n = n0 + row;
        if (n < N_CNT) {
            #pragma unroll
            for (int j = 0; j < 4; ++j) {
                int col = wn2 * 64 + 16 * j + (l & 15);
                nodes_out[(size_t)n * DD + col] =
                    acc2[j][r] + nb2c[j] + nodes[(size_t)n * DD + col];
            }
        }
    }
}

// ---------------------------------------------------------------------------
extern "C" void kernel_launch(void* const* d_in, const int* in_sizes, int n_in,
                              void* d_out, int out_size, void* d_ws, size_t ws_size,
                              hipStream_t stream) {
    const float* nodes = (const float*)d_in[0];
    const float* edges = (const float*)d_in[1];
    const int* senders = (const int*)d_in[2];
    const int* receivers = (const int*)d_in[3];
    const float* eW1 = (const float*)d_in[4];
    const float* eb1 = (const float*)d_in[5];
    const float* eg  = (const float*)d_in[6];
    const float* ebt = (const float*)d_in[7];
    const float* eW2 = (const float*)d_in[8];
    const float* eb2 = (const float*)d_in[9];
    const float* nW1 = (const float*)d_in[10];
    const float* nb1 = (const float*)d_in[11];
    const float* ng  = (const float*)d_in[12];
    const float* nbt = (const float*)d_in[13];
    const float* nW2 = (const float*)d_in[14];
    const float* nb2 = (const float*)d_in[15];

    char* ws = (char*)d_ws;
    short* aggBF = (short*)(ws + 0);            // 12,800,000 B [N][128] bf16
    short* eW1t  = (short*)(ws + 12800000);     //    196,608 B [256][384]
    short* eW2t  = (short*)(ws + 12996608);     //     65,536 B [128][256]
    short* nW1t  = (short*)(ws + 13062144);     //    131,072 B [256][256]
    short* nW2t  = (short*)(ws + 13193216);     //     65,536 B [128][256]
    short* eW1a  = (short*)(ws + 13258752);     //     65,536 B [256][128]
    short* tabS  = (short*)(ws + 13324288);     // 25,600,000 B [N][256]
    short* tabR  = (short*)(ws + 38924288);     // 25,600,000 B [N][256]

    float* nodes_out = (float*)d_out;
    float* edges_out = nodes_out + (size_t)N_CNT * DD;

    hipMemsetAsync(aggBF, 0, (size_t)N_CNT * DD * sizeof(short), stream);

    wtrans<<<(384 * 256 + 255) / 256, 256, 0, stream>>>(eW1, eW1t, 384, 256);
    wtrans<<<(256 * 128 + 255) / 256, 256, 0, stream>>>(eW2, eW2t, 256, 128);
    wtrans<<<(256 * 256 + 255) / 256, 256, 0, stream>>>(nW1, nW1t, 256, 256);
    wtrans<<<(256 * 128 + 255) / 256, 256, 0, stream>>>(nW2, nW2t, 256, 128);
    wtransA<<<(256 * 128 + 255) / 256, 256, 0, stream>>>(eW1, eW1a);

    table_kernel<<<(N_CNT + 127) / 128, 512, 0, stream>>>(nodes, eW1t, tabS, tabR);

    const int NTILE = (E_CNT + 31) / 32;               // 15625
    edge_kernel<<<(NTILE + TPB_E - 1) / TPB_E, 256, 0, stream>>>(
        edges, senders, receivers, tabS, tabR, eW1a, eW2t,
        eb1, eg, ebt, eb2, aggBF, edges_out);

    node_kernel<<<(N_CNT + 63) / 64, 512, 0, stream>>>(
        nodes, aggBF, nW1t, nW2t, nb1, ng, nbt, nb2, nodes_out);
}

// Round 15
// 602.832 us; speedup vs baseline: 2.9607x; 1.5191x over previous
//
#include <hip/hip_runtime.h>
#include <hip/hip_bf16.h>

#define E_CNT 500000
#define N_CNT 50000
#define DD 128
#define HH 256
#define LN_EPS 1e-5f

typedef __attribute__((ext_vector_type(8))) short bh8;   // 8 x bf16 (MFMA A/B frag)
typedef __attribute__((ext_vector_type(4))) float fx4;   // MFMA C/D frag

__device__ __forceinline__ float b2f(short s) {
    return __uint_as_float(((unsigned)(unsigned short)s) << 16);
}
// paired f32->bf16 RNE via v_cvt_pk_bf16_f32 (1 instr / 2 values)
__device__ __forceinline__ unsigned f2b2(float lo, float hi) {
    float2 t; t.x = lo; t.y = hi;
    __hip_bfloat162 h2 = __float22bfloat162_rn(t);
    union { __hip_bfloat162 h; unsigned u; } cv; cv.h = h2; return cv.u;
}
__device__ __forceinline__ short f2b(float f) {   // scalar (cold paths)
    unsigned x = __float_as_uint(f);
    x += 0x7fffu + ((x >> 16) & 1u);   // RNE
    return (short)(x >> 16);
}
__device__ __forceinline__ fx4 mfma16(bh8 a, bh8 b, fx4 c) {
    return __builtin_amdgcn_mfma_f32_16x16x32_bf16(a, b, c, 0, 0, 0);
}
__device__ __forceinline__ int swz128(int row, int k) {   // [*][128] bf16 tile
    return ((row * 128 + k) * 2) ^ ((row & 7) << 4);
}
__device__ __forceinline__ int swz256(int row, int c) {   // [*][256] bf16 tile
    return ((row * 256 + c) * 2) ^ ((row & 7) << 4);
}
__device__ __forceinline__ bh8 pack8(const float* s) {
    float4 f0 = *(const float4*)s, f1 = *(const float4*)(s + 4);
    union { unsigned u[4]; bh8 v; } cv;
    cv.u[0] = f2b2(f0.x, f0.y);
    cv.u[1] = f2b2(f0.z, f0.w);
    cv.u[2] = f2b2(f1.x, f1.y);
    cv.u[3] = f2b2(f1.z, f1.w);
    return cv.v;
}

// ---------------------------------------------------------------------------
// Fused weight prep (one launch replaces five):
//   idx space partitions: eW1t[256][384], eW2t[128][256], nW1t[256][256],
//   nW2t[128][256], eW1a[256][128]. dst[n][k] = bf16(src[k][n]).
// ---------------------------------------------------------------------------
__global__ void wprep(const float* __restrict__ eW1, const float* __restrict__ eW2,
                      const float* __restrict__ nW1, const float* __restrict__ nW2,
                      short* __restrict__ eW1t, short* __restrict__ eW2t,
                      short* __restrict__ nW1t, short* __restrict__ nW2t,
                      short* __restrict__ eW1a) {
    int idx = blockIdx.x * 256 + threadIdx.x;
    // segment sizes: 98304, 32768, 65536, 32768, 32768  (total 262144)
    if (idx < 98304) {                       // eW1t [256][384] from eW1[384][256]
        int n = idx / 384, k = idx - n * 384;
        eW1t[idx] = f2b(eW1[(size_t)k * 256 + n]);
    } else if (idx < 131072) {               // eW2t [128][256] from eW2[256][128]
        int i = idx - 98304;
        int n = i >> 8, k = i & 255;
        eW2t[i] = f2b(eW2[(size_t)k * 128 + n]);
    } else if (idx < 196608) {               // nW1t [256][256] from nW1[256][256]
        int i = idx - 131072;
        int n = i >> 8, k = i & 255;
        nW1t[i] = f2b(nW1[(size_t)k * 256 + n]);
    } else if (idx < 229376) {               // nW2t [128][256] from nW2[256][128]
        int i = idx - 196608;
        int n = i >> 8, k = i & 255;
        nW2t[i] = f2b(nW2[(size_t)k * 128 + n]);
    } else if (idx < 262144) {               // eW1a [256][128] from eW1[0:128][:]
        int i = idx - 229376;
        int n = i >> 7, k = i & 127;
        eW1a[i] = f2b(eW1[(size_t)k * 256 + n]);
    }
}

// ---------------------------------------------------------------------------
// Table precompute: tabS[n][h] = bf16(nodes[n]@eW1[128:256]),
//                   tabR[n][h] = bf16(nodes[n]@eW1[256:384]).
// ---------------------------------------------------------------------------
__launch_bounds__(512, 2)
__global__ void table_kernel(const float* __restrict__ nodes,
                             const short* __restrict__ eW1t,   // [256][384]
                             short* __restrict__ tabS, short* __restrict__ tabR) {
    __shared__ char Abuf[128 * 128 * 2];
    const int tid = threadIdx.x;
    const int l = tid & 63, wid = tid >> 6;
    const int wm = wid >> 2, wn = wid & 3;
    const int n0 = blockIdx.x * 128;

    for (int it = 0; it < 4; ++it) {
        int c = tid + 512 * it;
        int row = c >> 4, cc = (c & 15) * 8;
        int n = n0 + row; if (n >= N_CNT) n = N_CNT - 1;
        *(bh8*)(Abuf + swz128(row, cc)) = pack8(nodes + (size_t)n * DD + cc);
    }
    __syncthreads();

    fx4 accS[4][4] = {}; fx4 accR[4][4] = {};
    #pragma unroll
    for (int kk = 0; kk < 4; ++kk) {
        int krow = kk * 32 + (l >> 4) * 8;
        bh8 a[4], bs[4], br[4];
        #pragma unroll
        for (int i = 0; i < 4; ++i)
            a[i] = *(const bh8*)(Abuf + swz128(wm * 64 + 16 * i + (l & 15), krow));
        #pragma unroll
        for (int j = 0; j < 4; ++j) {
            const short* bp = eW1t + (size_t)(wn * 64 + 16 * j + (l & 15)) * 384 + krow;
            bs[j] = *(const bh8*)(bp + 128);
            br[j] = *(const bh8*)(bp + 256);
        }
        #pragma unroll
        for (int i = 0; i < 4; ++i)
            #pragma unroll
            for (int j = 0; j < 4; ++j) {
                accS[i][j] = mfma16(a[i], bs[j], accS[i][j]);
                accR[i][j] = mfma16(a[i], br[j], accR[i][j]);
            }
    }
    #pragma unroll
    for (int i = 0; i < 4; ++i)
        #pragma unroll
        for (int r = 0; r < 4; ++r) {
            int row = wm * 64 + 16 * i + (l >> 4) * 4 + r;
            int n = n0 + row;
            if (n < N_CNT) {
                unsigned s01 = f2b2(accS[i][0][r], accS[i][1][r]);
                unsigned s23 = f2b2(accS[i][2][r], accS[i][3][r]);
                unsigned r01 = f2b2(accR[i][0][r], accR[i][1][r]);
                unsigned r23 = f2b2(accR[i][2][r], accR[i][3][r]);
                size_t base = (size_t)n * HH + (l & 15);
                tabS[base + wn * 64 +  0] = (short)s01;
                tabS[base + wn * 64 + 16] = (short)(s01 >> 16);
                tabS[base + wn * 64 + 32] = (short)s23;
                tabS[base + wn * 64 + 48] = (short)(s23 >> 16);
                tabR[base + wn * 64 +  0] = (short)r01;
                tabR[base + wn * 64 + 16] = (short)(r01 >> 16);
                tabR[base + wn * 64 + 32] = (short)r23;
                tabR[base + wn * 64 + 48] = (short)(r23 >> 16);
            }
        }
}

// ---------------------------------------------------------------------------
// Edge kernel (R12, best measured: 524us): 256 thr / BM=32 / 4 blocks/CU.
//   pre = edges@W1a (K=128 MFMA) + tabS[s]+tabR[r] + eb1
//   h   = relu(LN(pre)) -> Sbuf;  upd = h@eW2 + eb2
//   edges_out = upd + residual(Abuf);  packed-bf16 atomic scatter to aggBF.
// ---------------------------------------------------------------------------
__launch_bounds__(256, 4)
__global__ void edge_kernel(const float* __restrict__ edges,
                            const int* __restrict__ senders,
                            const int* __restrict__ receivers,
                            const short* __restrict__ tabS,
                            const short* __restrict__ tabR,
                            const short* __restrict__ eW1a,   // [256][128]
                            const short* __restrict__ eW2t,   // [128][256]
                            const float* __restrict__ eb1,
                            const float* __restrict__ eg,
                            const float* __restrict__ ebt,
                            const float* __restrict__ eb2,
                            short* __restrict__ aggBF,        // [N][128] bf16
                            float* __restrict__ edges_out) {
    __shared__ short Abuf[32 * 128];     //  8KB edges tile (bf16, swizzled)
    __shared__ short Sbuf[32 * 256];     // 16KB table-sum, later H
    __shared__ float P[32][4][2];        //  1KB LN partials
    __shared__ int irecv[32];

    const int tid = threadIdx.x;
    const int l = tid & 63, wid = tid >> 6, lg = l >> 4, lo = l & 15;
    const int e0 = blockIdx.x * 32;

    if (tid < 32) {
        int e = e0 + tid; if (e >= E_CNT) e = E_CNT - 1;
        irecv[tid] = receivers[e];
    }

    // ---- stage A: 32 rows x 128 cols; 512 chunks / 256 thr = 2 each ----
    #pragma unroll
    for (int it = 0; it < 2; ++it) {
        int ch = tid + 256 * it;
        int row = ch >> 4, c = (ch & 15) * 8;
        int e = e0 + row; if (e >= E_CNT) e = E_CNT - 1;
        *(bh8*)((char*)Abuf + swz128(row, c)) = pack8(edges + (size_t)e * DD + c);
    }
    // ---- issue table gathers into regs (consumed after GEMM1) ----
    bh8 ts[4], tr[4];
    #pragma unroll
    for (int it = 0; it < 4; ++it) {
        int ch = tid + 256 * it;                 // 1024 chunks of 8 bf16
        int row = ch >> 5, cc = (ch & 31) * 8;
        int e = e0 + row; if (e >= E_CNT) e = E_CNT - 1;
        ts[it] = *(const bh8*)(tabS + (size_t)senders[e] * HH + cc);
        tr[it] = *(const bh8*)(tabR + (size_t)receivers[e] * HH + cc);
    }
    __syncthreads();

    // ---- GEMM1: A[32x128] @ W1a -> acc[32x256]; wave = 32 rows x 64 cols ----
    const int wn = wid;                          // 4 waves = 4 col groups
    fx4 acc[2][4] = {};
    #pragma unroll
    for (int kk = 0; kk < 4; ++kk) {
        int krow = kk * 32 + lg * 8;
        bh8 a[2], b[4];
        #pragma unroll
        for (int i = 0; i < 2; ++i)
            a[i] = *(const bh8*)((char*)Abuf + swz128(16 * i + lo, krow));
        #pragma unroll
        for (int j = 0; j < 4; ++j)
            b[j] = *(const bh8*)(eW1a + (size_t)(wn * 64 + 16 * j + lo) * 128 + krow);
        #pragma unroll
        for (int i = 0; i < 2; ++i)
            #pragma unroll
            for (int j = 0; j < 4; ++j)
                acc[i][j] = mfma16(a[i], b[j], acc[i][j]);
    }

    // ---- combine gathered tables -> Sbuf (paired cvt) ----
    #pragma unroll
    for (int it = 0; it < 4; ++it) {
        int ch = tid + 256 * it;
        int row = ch >> 5, cc = (ch & 31) * 8;
        union { unsigned u[4]; bh8 v; } cv;
        #pragma unroll
        for (int q = 0; q < 4; ++q) {
            float s0 = b2f(ts[it][2 * q])     + b2f(tr[it][2 * q]);
            float s1 = b2f(ts[it][2 * q + 1]) + b2f(tr[it][2 * q + 1]);
            cv.u[q] = f2b2(s0, s1);
        }
        *(bh8*)((char*)Sbuf + swz256(row, cc)) = cv.v;
    }
    __syncthreads();

    // ---- epilogue 1: + table-sum + eb1, LN partials ----
    float eb1c[4], egc[4], ebtc[4];
    #pragma unroll
    for (int j = 0; j < 4; ++j) {
        int col = wn * 64 + 16 * j + lo;
        eb1c[j] = eb1[col]; egc[j] = eg[col]; ebtc[j] = ebt[col];
    }
    #pragma unroll
    for (int i = 0; i < 2; ++i)
        #pragma unroll
        for (int r = 0; r < 4; ++r) {
            int row = 16 * i + lg * 4 + r;
            float s = 0.f, q = 0.f;
            #pragma unroll
            for (int j = 0; j < 4; ++j) {
                int col = wn * 64 + 16 * j + lo;
                float v = acc[i][j][r] + eb1c[j] +
                          b2f(*(const short*)((char*)Sbuf + swz256(row, col)));
                acc[i][j][r] = v;
                s += v; q += v * v;
            }
            #pragma unroll
            for (int m = 1; m < 16; m <<= 1) {
                s += __shfl_xor(s, m);
                q += __shfl_xor(q, m);
            }
            if (lo == 0) { P[row][wn][0] = s; P[row][wn][1] = q; }
        }
    __syncthreads();   // Sbuf reads done; partials visible

    // ---- epilogue 2: LN + relu -> H into Sbuf ----
    #pragma unroll
    for (int i = 0; i < 2; ++i)
        #pragma unroll
        for (int r = 0; r < 4; ++r) {
            int row = 16 * i + lg * 4 + r;
            float s = P[row][0][0] + P[row][1][0] + P[row][2][0] + P[row][3][0];
            float q = P[row][0][1] + P[row][1][1] + P[row][2][1] + P[row][3][1];
            float mean = s * (1.0f / 256.0f);
            float var = q * (1.0f / 256.0f) - mean * mean;
            float rstd = rsqrtf(var + LN_EPS);
            float hv[4];
            #pragma unroll
            for (int j = 0; j < 4; ++j) {
                float v = (acc[i][j][r] - mean) * rstd * egc[j] + ebtc[j];
                hv[j] = fmaxf(v, 0.0f);
            }
            unsigned p01 = f2b2(hv[0], hv[1]);
            unsigned p23 = f2b2(hv[2], hv[3]);
            *(short*)((char*)Sbuf + swz256(row, wn * 64 +  0 + lo)) = (short)p01;
            *(short*)((char*)Sbuf + swz256(row, wn * 64 + 16 + lo)) = (short)(p01 >> 16);
            *(short*)((char*)Sbuf + swz256(row, wn * 64 + 32 + lo)) = (short)p23;
            *(short*)((char*)Sbuf + swz256(row, wn * 64 + 48 + lo)) = (short)(p23 >> 16);
        }
    __syncthreads();

    // ---- GEMM2: H[32x256] @ eW2 -> [32x128]; wave = 16 rows x 64 cols ----
    const int wm2 = wid >> 1, wn2 = wid & 1;
    fx4 acc2[4] = {};
    #pragma unroll
    for (int kk = 0; kk < 8; ++kk) {
        int krow = kk * 32 + lg * 8;
        bh8 a = *(const bh8*)((char*)Sbuf + swz256(wm2 * 16 + lo, krow));
        #pragma unroll
        for (int j = 0; j < 4; ++j) {
            bh8 b = *(const bh8*)(eW2t + (size_t)(wn2 * 64 + 16 * j + lo) * HH + krow);
            acc2[j] = mfma16(a, b, acc2[j]);
        }
    }
    float eb2c[4];
    #pragma unroll
    for (int j = 0; j < 4; ++j) eb2c[j] = eb2[wn2 * 64 + 16 * j + lo];
    #pragma unroll
    for (int r = 0; r < 4; ++r) {
        int row = wm2 * 16 + lg * 4 + r;
        int e = e0 + row;
        int rcv = irecv[row];
        #pragma unroll
        for (int j = 0; j < 4; ++j) {
            int col = wn2 * 64 + 16 * j + lo;
            float upd = acc2[j][r] + eb2c[j];
            // pair-exchange for packed atomic: adjacent cols sit in lane^1
            float par = __shfl_xor(upd, 1);
            if (e < E_CNT) {
                float res = b2f(*(const short*)((char*)Abuf + swz128(row, col)));
                edges_out[(size_t)e * DD + col] = upd + res;
                if ((lo & 1) == 0) {
                    unsigned pk = f2b2(upd, par);   // one v_cvt_pk_bf16_f32
                    short* p = aggBF + (size_t)rcv * DD + col;
                    asm volatile("global_atomic_pk_add_bf16 %0, %1, off"
                                 :: "v"(p), "v"(pk) : "memory");
                }
            }
        }
    }
}

// ---------------------------------------------------------------------------
// Node kernel: nx=[nodes|aggBF] -> GEMM1 (K=256) -> LN/relu -> GEMM2 + nb2 + nodes
// ---------------------------------------------------------------------------
__launch_bounds__(512, 2)
__global__ void node_kernel(const float* __restrict__ nodes,
                            const short* __restrict__ aggBF,  // [N][128] bf16
                            const short* __restrict__ nW1t,   // [256][256]
                            const short* __restrict__ nW2t,   // [128][256]
                            const float* __restrict__ nb1,
                            const float* __restrict__ ng,
                            const float* __restrict__ nbt,
                            const float* __restrict__ nb2,
                            float* __restrict__ nodes_out) {
    __shared__ char X[64 * 256 * 2];
    __shared__ float P[64][4][2];

    const int tid = threadIdx.x;
    const int l = tid & 63, wid = tid >> 6;
    const int n0 = blockIdx.x * 64;

    #pragma unroll
    for (int it = 0; it < 4; ++it) {
        int c = tid + 512 * it;
        int row = c >> 5, cc = (c & 31) * 8;
        int n = n0 + row; if (n >= N_CNT) n = N_CNT - 1;
        bh8 v;
        if (cc < DD) v = pack8(nodes + (size_t)n * DD + cc);
        else         v = *(const bh8*)(aggBF + (size_t)n * DD + (cc - DD));
        *(bh8*)(X + swz256(row, cc)) = v;
    }
    __syncthreads();

    const int wm = wid >> 2, wn = wid & 3;
    fx4 acc[2][4] = {};
    #pragma unroll
    for (int kk = 0; kk < 8; ++kk) {
        int krow = kk * 32 + (l >> 4) * 8;
        bh8 a[2], b[4];
        #pragma unroll
        for (int i = 0; i < 2; ++i)
            a[i] = *(const bh8*)(X + swz256(wm * 32 + 16 * i + (l & 15), krow));
        #pragma unroll
        for (int j = 0; j < 4; ++j)
            b[j] = *(const bh8*)(nW1t + (size_t)(wn * 64 + 16 * j + (l & 15)) * 256 + krow);
        #pragma unroll
        for (int i = 0; i < 2; ++i)
            #pragma unroll
            for (int j = 0; j < 4; ++j)
                acc[i][j] = mfma16(a[i], b[j], acc[i][j]);
    }
    __syncthreads();

    float nb1c[4], ngc[4], nbtc[4];
    #pragma unroll
    for (int j = 0; j < 4; ++j) {
        int col = wn * 64 + 16 * j + (l & 15);
        nb1c[j] = nb1[col]; ngc[j] = ng[col]; nbtc[j] = nbt[col];
    }
    #pragma unroll
    for (int i = 0; i < 2; ++i)
        #pragma unroll
        for (int r = 0; r < 4; ++r) {
            int row = wm * 32 + 16 * i + (l >> 4) * 4 + r;
            float s = 0.f, q = 0.f;
            #pragma unroll
            for (int j = 0; j < 4; ++j) {
                float v = acc[i][j][r] + nb1c[j];
                acc[i][j][r] = v;
                s += v; q += v * v;
            }
            #pragma unroll
            for (int m = 1; m < 16; m <<= 1) {
                s += __shfl_xor(s, m);
                q += __shfl_xor(q, m);
            }
            if ((l & 15) == 0) { P[row][wn][0] = s; P[row][wn][1] = q; }
        }
    __syncthreads();

    #pragma unroll
    for (int i = 0; i < 2; ++i)
        #pragma unroll
        for (int r = 0; r < 4; ++r) {
            int row = wm * 32 + 16 * i + (l >> 4) * 4 + r;
            float s = P[row][0][0] + P[row][1][0] + P[row][2][0] + P[row][3][0];
            float q = P[row][0][1] + P[row][1][1] + P[row][2][1] + P[row][3][1];
            float mean = s * (1.0f / 256.0f);
            float var = q * (1.0f / 256.0f) - mean * mean;
            float rstd = rsqrtf(var + LN_EPS);
            float hv[4];
            #pragma unroll
            for (int j = 0; j < 4; ++j) {
                float v = (acc[i][j][r] - mean) * rstd * ngc[j] + nbtc[j];
                hv[j] = fmaxf(v, 0.0f);
            }
            unsigned p01 = f2b2(hv[0], hv[1]);
            unsigned p23 = f2b2(hv[2], hv[3]);
            int c0 = wn * 64 + (l & 15);
            *(short*)(X + swz256(row, c0 +  0)) = (short)p01;
            *(short*)(X + swz256(row, c0 + 16)) = (short)(p01 >> 16);
            *(short*)(X + swz256(row, c0 + 32)) = (short)p23;
            *(short*)(X + swz256(row, c0 + 48)) = (short)(p23 >> 16);
        }
    __syncthreads();

    const int wm2 = wid >> 1, wn2 = wid & 1;
    fx4 acc2[4] = {};
    #pragma unroll
    for (int kk = 0; kk < 8; ++kk) {
        int krow = kk * 32 + (l >> 4) * 8;
        bh8 a = *(const bh8*)(X + swz256(wm2 * 16 + (l & 15), krow));
        #pragma unroll
        for (int j = 0; j < 4; ++j) {
            bh8 b = *(const bh8*)(nW2t + (size_t)(wn2 * 64 + 16 * j + (l & 15)) * 256 + krow);
            acc2[j] = mfma16(a, b, acc2[j]);
        }
    }
    float nb2c[4];
    #pragma unroll
    for (int j = 0; j < 4; ++j) nb2c[j] = nb2[wn2 * 64 + 16 * j + (l & 15)];
    #pragma unroll
    for (int r = 0; r < 4; ++r) {
        int row = wm2 * 16 + (l >> 4) * 4 + r;
        int n = n0 + row;
        if (n < N_CNT) {
            #pragma unroll
            for (int j = 0; j < 4; ++j) {
                int col = wn2 * 64 + 16 * j + (l & 15);
                nodes_out[(size_t)n * DD + col] =
                    acc2[j][r] + nb2c[j] + nodes[(size_t)n * DD + col];
            }
        }
    }
}

// ---------------------------------------------------------------------------
extern "C" void kernel_launch(void* const* d_in, const int* in_sizes, int n_in,
                              void* d_out, int out_size, void* d_ws, size_t ws_size,
                              hipStream_t stream) {
    const float* nodes = (const float*)d_in[0];
    const float* edges = (const float*)d_in[1];
    const int* senders = (const int*)d_in[2];
    const int* receivers = (const int*)d_in[3];
    const float* eW1 = (const float*)d_in[4];
    const float* eb1 = (const float*)d_in[5];
    const float* eg  = (const float*)d_in[6];
    const float* ebt = (const float*)d_in[7];
    const float* eW2 = (const float*)d_in[8];
    const float* eb2 = (const float*)d_in[9];
    const float* nW1 = (const float*)d_in[10];
    const float* nb1 = (const float*)d_in[11];
    const float* ng  = (const float*)d_in[12];
    const float* nbt = (const float*)d_in[13];
    const float* nW2 = (const float*)d_in[14];
    const float* nb2 = (const float*)d_in[15];

    char* ws = (char*)d_ws;
    short* aggBF = (short*)(ws + 0);            // 12,800,000 B [N][128] bf16
    short* eW1t  = (short*)(ws + 12800000);     //    196,608 B [256][384]
    short* eW2t  = (short*)(ws + 12996608);     //     65,536 B [128][256]
    short* nW1t  = (short*)(ws + 13062144);     //    131,072 B [256][256]
    short* nW2t  = (short*)(ws + 13193216);     //     65,536 B [128][256]
    short* eW1a  = (short*)(ws + 13258752);     //     65,536 B [256][128]
    short* tabS  = (short*)(ws + 13324288);     // 25,600,000 B [N][256]
    short* tabR  = (short*)(ws + 38924288);     // 25,600,000 B [N][256]

    float* nodes_out = (float*)d_out;
    float* edges_out = nodes_out + (size_t)N_CNT * DD;

    hipMemsetAsync(aggBF, 0, (size_t)N_CNT * DD * sizeof(short), stream);

    wprep<<<(262144 + 255) / 256, 256, 0, stream>>>(
        eW1, eW2, nW1, nW2, eW1t, eW2t, nW1t, nW2t, eW1a);

    table_kernel<<<(N_CNT + 127) / 128, 512, 0, stream>>>(nodes, eW1t, tabS, tabR);

    edge_kernel<<<(E_CNT + 31) / 32, 256, 0, stream>>>(
        edges, senders, receivers, tabS, tabR, eW1a, eW2t,
        eb1, eg, ebt, eb2, aggBF, edges_out);

    node_kernel<<<(N_CNT + 63) / 64, 512, 0, stream>>>(
        nodes, aggBF, nW1t, nW2t, nb1, ng, nbt, nb2, nodes_out);
}